// Round 10
// baseline (312.242 us; speedup 1.0000x reference)
//
#include <hip/hip_runtime.h>
#include <hip/hip_bf16.h>
#include <math.h>

#define DM 768
#define NBATCH 2
#define TIMEN 196
#define SPACEF 8
#define SEQL 1569          // 1 + 196*8
#define NSTATE 16
#define MT 3136            // mamba tokens = 2*196*8
#define NSEQ 392           // mamba sequences = 2*196, each length 8
#define AT 3152            // attn tokens = 16*197
#define XTOK 3138          // 2*1569

typedef __attribute__((ext_vector_type(8))) short s16x8;
typedef __attribute__((ext_vector_type(4))) float f32x4;
typedef __hip_bfloat16 bf16;

__device__ __forceinline__ float silu_fast(float x){ return __fdividef(x, 1.0f + __expf(-x)); }
// tanh-form GELU, overflow-safe (max err vs exact-erf gelu ~1e-3)
__device__ __forceinline__ float geluf(float x){
  float y = 0.7978845608f * (x + 0.044715f*x*x*x);
  float ay = fabsf(y);
  float e = __expf(-2.0f*ay);
  float t = __fdividef(1.0f - e, 1.0f + e);
  t = copysignf(t, y);
  return 0.5f*x*(1.0f + t);
}
__device__ __forceinline__ float softplusf(float x){
  return (x > 20.0f) ? x : __logf(1.0f + __expf(x));
}
__device__ __forceinline__ int imin(int a, int b){ return a < b ? a : b; }

#define GLD_LDS16(g, l) __builtin_amdgcn_global_load_lds( \
    (const __attribute__((address_space(1))) void*)(g), \
    (__attribute__((address_space(3))) void*)(l), 16, 0, 0)

// ---------------- weight fp32 -> padded bf16 pool ----------------
template<int N, int K, int Np, int Kp>
__device__ __forceinline__ void cvt_seg(const float* __restrict__ src, bf16* __restrict__ dst){
  const int total = Np * Kp;
  int base = blockIdx.x * 1024 + threadIdx.x;
  #pragma unroll
  for (int e = 0; e < 4; e++){
    int idx = base + e * 256;
    if (idx < total){
      int n = idx / Kp, k = idx % Kp;
      float v = (n < N && k < K) ? src[n * K + k] : 0.0f;
      dst[idx] = __float2bfloat16(v);
    }
  }
}

__global__ __launch_bounds__(256) void cvtw_kernel(
    const float* s0, const float* s1, const float* s2, const float* s3,
    const float* s4, const float* s5, const float* s6, const float* s7,
    const float* s8, const float* s9, bf16* w)
{
  switch (blockIdx.y) {
    case 0: cvt_seg<1536,768,1536,768>(s0, w + 0);        break; // m_in_w
    case 1: cvt_seg<  80,768, 128,768>(s1, w + 1179648);  break; // xproj f
    case 2: cvt_seg<  80,768, 128,768>(s2, w + 1277952);  break; // xproj b
    case 3: cvt_seg< 768, 48, 768, 64>(s3, w + 1376256);  break; // dt f (K zero-pad)
    case 4: cvt_seg< 768, 48, 768, 64>(s4, w + 1425408);  break; // dt b
    case 5: cvt_seg< 768,768, 768,768>(s5, w + 1474560);  break; // m_out_w
    case 6: cvt_seg<2304,768,2304,768>(s6, w + 2064384);  break; // attn_in_w
    case 7: cvt_seg< 768,768, 768,768>(s7, w + 3833856);  break; // attn_out_w
    case 8: cvt_seg<3072,768,3072,768>(s8, w + 4423680);  break; // fc1
    default:cvt_seg< 768,3072,768,3072>(s9, w + 6782976); break; // fc2
  }
}

// ---------------- block row sum helper ----------------
__device__ __forceinline__ float block_sum256(float v, float* sm){
  #pragma unroll
  for (int o = 32; o > 0; o >>= 1) v += __shfl_down(v, o);
  __syncthreads();
  if ((threadIdx.x & 63) == 0) sm[threadIdx.x >> 6] = v;
  __syncthreads();
  return sm[0] + sm[1] + sm[2] + sm[3];
}

// ---------------- LN over xt gather ----------------
__global__ __launch_bounds__(256) void ln_kernel(
    const float* __restrict__ src0,
    const float* __restrict__ w, const float* __restrict__ b,
    bf16* __restrict__ out)
{
  __shared__ float sm[4];
  int tok = blockIdx.x;
  int bi = tok / (TIMEN*SPACEF), r = tok % (TIMEN*SPACEF);
  const float* src = src0 + ((size_t)bi * SEQL + 1 + r) * DM;
  int tid = threadIdx.x;
  float xr[3];
  #pragma unroll
  for (int i = 0; i < 3; i++) xr[i] = src[tid + i*256];
  float mean = block_sum256(xr[0]+xr[1]+xr[2], sm) * (1.0f/768.0f);
  float v0 = xr[0]-mean, v1 = xr[1]-mean, v2 = xr[2]-mean;
  float var = block_sum256(v0*v0 + v1*v1 + v2*v2, sm) * (1.0f/768.0f);
  float rstd = rsqrtf(var + 1e-5f);
  bf16* o = out + (size_t)tok * DM;
  #pragma unroll
  for (int i = 0; i < 3; i++){ int c = tid + i*256;
    o[c] = __float2bfloat16((xr[i]-mean)*rstd*w[c] + b[c]); }
}

// ---------------- fused out-proj reduce + LN1 (xs gather) -> xsln bf16 ----------------
__global__ __launch_bounds__(256) void redk_ln(
    const float* __restrict__ part, const float* __restrict__ x,
    const float* __restrict__ w, const float* __restrict__ b,
    bf16* __restrict__ out)
{
  __shared__ float sm[4];
  int tok = blockIdx.x;
  int sidx = tok / 197, p = tok % 197;
  int tid = threadIdx.x;
  float xr[3];
  if (p == 0) {
    const float* src = x + (size_t)(sidx >> 3) * SEQL * DM;
    #pragma unroll
    for (int i = 0; i < 3; i++) xr[i] = src[tid + i*256];
  } else {
    int bi = sidx >> 3, f = sidx & 7, t = p - 1;
    size_t mt = ((size_t)(bi*TIMEN + t))*SPACEF + f;
    const float* p0 = part + mt*DM;
    const float* p1 = part + ((size_t)MT + mt)*DM;
    const float* xs = x + ((size_t)bi*SEQL + 1 + t*SPACEF + f)*DM;
    #pragma unroll
    for (int i = 0; i < 3; i++){ int c = tid + i*256;
      xr[i] = p0[c] + p1[c] + xs[c]; }
  }
  float mean = block_sum256(xr[0]+xr[1]+xr[2], sm) * (1.0f/768.0f);
  float v0 = xr[0]-mean, v1 = xr[1]-mean, v2 = xr[2]-mean;
  float var = block_sum256(v0*v0 + v1*v1 + v2*v2, sm) * (1.0f/768.0f);
  float rstd = rsqrtf(var + 1e-5f);
  bf16* o = out + (size_t)tok * DM;
  #pragma unroll
  for (int i = 0; i < 3; i++){ int c = tid + i*256;
    o[c] = __float2bfloat16((xr[i]-mean)*rstd*w[c] + b[c]); }
}

// ---------------- fused attn-out reduce + scatter + LN2 ----------------
__global__ __launch_bounds__(256) void scatter_ln(
    const float* __restrict__ part, const float* __restrict__ bias,
    const float* __restrict__ x, float* __restrict__ xnew,
    const float* __restrict__ w, const float* __restrict__ b,
    bf16* __restrict__ out)
{
  __shared__ float sm[4];
  int tok = blockIdx.x;
  int bi = tok / SEQL, row = tok % SEQL;
  int tid = threadIdx.x;
  const float* p1 = part + (size_t)AT*DM;
  const float* xs = x + (size_t)tok*DM;
  float xr[3];
  if (row == 0) {
    #pragma unroll
    for (int i = 0; i < 3; i++){ int c = tid + i*256;
      float acc = 0.0f;
      #pragma unroll
      for (int f = 0; f < SPACEF; f++){
        size_t r = ((size_t)(bi*SPACEF + f)*197)*DM + c;
        acc += part[r] + p1[r];
      }
      xr[i] = xs[c] + acc * 0.125f + bias[c];
    }
  } else {
    int t = (row - 1) >> 3, f = (row - 1) & 7;
    size_t r = ((size_t)((bi*SPACEF + f)*197) + 1 + t)*DM;
    #pragma unroll
    for (int i = 0; i < 3; i++){ int c = tid + i*256;
      xr[i] = xs[c] + part[r + c] + p1[r + c] + bias[c];
    }
  }
  float* xo = xnew + (size_t)tok*DM;
  #pragma unroll
  for (int i = 0; i < 3; i++) xo[tid + i*256] = xr[i];
  float mean = block_sum256(xr[0]+xr[1]+xr[2], sm) * (1.0f/768.0f);
  float v0 = xr[0]-mean, v1 = xr[1]-mean, v2 = xr[2]-mean;
  float var = block_sum256(v0*v0 + v1*v1 + v2*v2, sm) * (1.0f/768.0f);
  float rstd = rsqrtf(var + 1e-5f);
  bf16* o = out + (size_t)tok*DM;
  #pragma unroll
  for (int i = 0; i < 3; i++){ int c = tid + i*256;
    o[c] = __float2bfloat16((xr[i]-mean)*rstd*w[c] + b[c]); }
}

// ======= 4-wave 64x64 BK=64 GEMM (kept for xproj/dt padded shapes) =======
template<int BM, int BN>
__global__ __launch_bounds__(256) void mgemm(
    const bf16* __restrict__ A, int lda,
    const bf16* __restrict__ W0, const bf16* __restrict__ W1, int ldw,
    const float* __restrict__ bias0, const float* __restrict__ bias1,
    void* __restrict__ Cout, int M, int mhalf, int N, int ldc, int KP,
    int act, int outbf16)
{
  constexpr int WM = BM/2, WN = BN/2, MI = WM/16, NJ = WN/16;
  __shared__ bf16 As[2][BM*64];
  __shared__ bf16 Bs[2][BN*64];
  int tid = threadIdx.x;
  int wave = tid >> 6, lane = tid & 63;

  int gx = gridDim.x;
  int nwg = gx * gridDim.y;
  int bid = blockIdx.y * gx + blockIdx.x;
  int q = nwg >> 3, r = nwg & 7;
  int xcd = bid & 7, lidx = bid >> 3;
  int wg = (xcd < r ? xcd*(q+1) : r*(q+1) + (xcd-r)*q) + lidx;
  int m0 = (wg / gx) * BM, n0 = (wg % gx) * BN;

  int wr = wave >> 1, wc = wave & 1;
  const bf16* Wt = ((m0 < mhalf) ? W0 : W1);
  const float* bias = (m0 < mhalf) ? bias0 : bias1;

  f32x4 acc[MI][NJ];
  #pragma unroll
  for (int i = 0; i < MI; i++)
    #pragma unroll
    for (int j = 0; j < NJ; j++) acc[i][j] = (f32x4){0.f,0.f,0.f,0.f};

  int sr8 = lane >> 3;
  int scs = (((lane & 7) ^ sr8) * 8);
  int lr16 = lane & 15, ks = (lane >> 4) * 8;
  int swz = (lr16 & 7) << 3;

  auto stage = [&](int buf, int k0){
    #pragma unroll
    for (int g = 0; g < BM/32; g++){
      int rr = wave*(BM/4) + g*8;
      const bf16* ga = A + (size_t)imin(m0 + rr + sr8, M-1)*lda + k0 + scs;
      GLD_LDS16(ga, &As[buf][rr*64]);
    }
    #pragma unroll
    for (int g = 0; g < BN/32; g++){
      int rr = wave*(BN/4) + g*8;
      const bf16* gb = Wt + (size_t)(n0 + rr + sr8)*ldw + k0 + scs;
      GLD_LDS16(gb, &Bs[buf][rr*64]);
    }
  };

  auto compute = [&](int buf){
    s16x8 afr[2][MI], bfr[2][NJ];
    #pragma unroll
    for (int kk = 0; kk < 2; kk++){
      #pragma unroll
      for (int i = 0; i < MI; i++)
        afr[kk][i] = *(const s16x8*)&As[buf][(wr*WM + i*16 + lr16)*64 + ((kk*32 + ks) ^ swz)];
      #pragma unroll
      for (int j = 0; j < NJ; j++)
        bfr[kk][j] = *(const s16x8*)&Bs[buf][(wc*WN + j*16 + lr16)*64 + ((kk*32 + ks) ^ swz)];
    }
    #pragma unroll
    for (int kk = 0; kk < 2; kk++)
      #pragma unroll
      for (int i = 0; i < MI; i++)
        #pragma unroll
        for (int j = 0; j < NJ; j++)
          acc[i][j] = __builtin_amdgcn_mfma_f32_16x16x32_bf16(afr[kk][i], bfr[kk][j], acc[i][j], 0, 0, 0);
  };

  stage(0, 0);
  __syncthreads();
  int cur = 0;
  for (int k0 = 64; k0 < KP; k0 += 64){
    stage(cur ^ 1, k0);
    compute(cur);
    __syncthreads();
    cur ^= 1;
  }
  compute(cur);

  #pragma unroll
  for (int i = 0; i < MI; i++){
    int rowb = m0 + wr*WM + i*16 + (lane >> 4)*4;
    #pragma unroll
    for (int j = 0; j < NJ; j++){
      int col = n0 + wc*WN + j*16 + lr16;
      if (col >= N) continue;
      float bv = bias ? bias[col] : 0.0f;
      #pragma unroll
      for (int r2 = 0; r2 < 4; r2++){
        int row = rowb + r2;
        if (row >= M) continue;
        float v = acc[i][j][r2] + bv;
        if (act == 2) v = softplusf(v);
        if (outbf16) ((bf16*)Cout)[(size_t)row*ldc + col] = __float2bfloat16(v);
        else         ((float*)Cout)[(size_t)row*ldc + col] = v;
      }
    }
  }
}

// ======= 2-wave 64x128 BK=32 GEMM, wave-tile 64x64 (0.5KB LDS/MFMA) =======
// skw==1: C = act(A @ W0^T + bias0); skw>1: fp32 partial [z][M][ldc], K slice KP
__global__ __launch_bounds__(128) void mgemm2(
    const bf16* __restrict__ A, int lda,
    const bf16* __restrict__ W0, int ldw,
    const float* __restrict__ bias0,
    void* __restrict__ Cout, int M, int N, int ldc, int KP,
    int act, int outbf16, int skw)
{
  __shared__ bf16 As[2][64*32];
  __shared__ bf16 Bs[2][128*32];
  int tid = threadIdx.x;
  int wave = tid >> 6, lane = tid & 63;

  // XCD-aware placement
  int gx = gridDim.x, gy = gridDim.y;
  int nwg = gx * gy;
  int bid = blockIdx.y * gx + blockIdx.x;
  int m0, n0;
  if ((gx & 3) == 0 && (gy & 1) == 0) {
    int cw = gx >> 2, rh = gy >> 1;
    int xcd = bid & 7, lidx = bid >> 3;
    int rx = xcd & 3, ry = xcd >> 2;
    m0 = ((ry * rh) + lidx / cw) * 64;
    n0 = ((rx * cw) + lidx % cw) * 128;
  } else {
    int q = nwg >> 3, r = nwg & 7;
    int xcd = bid & 7, lidx = bid >> 3;
    int wg = (xcd < r ? xcd*(q+1) : r*(q+1) + (xcd-r)*q) + lidx;
    m0 = (wg / gx) * 64; n0 = (wg % gx) * 128;
  }

  int koff = blockIdx.z * KP;
  const bf16* Ak = A + koff;
  const bf16* Wt = W0 + koff;

  f32x4 acc[4][4];
  #pragma unroll
  for (int i = 0; i < 4; i++)
    #pragma unroll
    for (int j = 0; j < 4; j++) acc[i][j] = (f32x4){0.f,0.f,0.f,0.f};

  // stage: each call = 128 thr x 16B = 2KB = 32 rows of 64B. row-in-call =
  // wave*16 + (lane>>2); slot = lane&3. Source col pre-XORed by (row>>1)&3
  // = (lane>>3)&3 so linear LDS dest == swizzled layout.
  int srow = lane >> 2;
  int scs = ((lane & 3) ^ ((lane >> 3) & 3)) * 8;
  int lr16 = lane & 15, ks = (lane >> 4) * 8;
  int swz = ((lr16 >> 1) & 3) << 3;

  auto stage = [&](int buf, int k0){
    #pragma unroll
    for (int g = 0; g < 2; g++){
      int rb = g*32 + wave*16;
      const bf16* ga = Ak + (size_t)imin(m0 + rb + srow, M-1)*lda + k0 + scs;
      GLD_LDS16(ga, &As[buf][rb*32]);
    }
    #pragma unroll
    for (int g = 0; g < 4; g++){
      int rb = g*32 + wave*16;
      const bf16* gb = Wt + (size_t)(n0 + rb + srow)*ldw + k0 + scs;
      GLD_LDS16(gb, &Bs[buf][rb*32]);
    }
  };

  auto compute = [&](int buf){
    s16x8 afr[4], bfr[4];
    #pragma unroll
    for (int i = 0; i < 4; i++)
      afr[i] = *(const s16x8*)&As[buf][(i*16 + lr16)*32 + (ks ^ swz)];
    #pragma unroll
    for (int j = 0; j < 4; j++)
      bfr[j] = *(const s16x8*)&Bs[buf][(wave*64 + j*16 + lr16)*32 + (ks ^ swz)];
    #pragma unroll
    for (int i = 0; i < 4; i++)
      #pragma unroll
      for (int j = 0; j < 4; j++)
        acc[i][j] = __builtin_amdgcn_mfma_f32_16x16x32_bf16(afr[i], bfr[j], acc[i][j], 0, 0, 0);
  };

  stage(0, 0);
  __syncthreads();
  int cur = 0;
  for (int k0 = 32; k0 < KP; k0 += 32){
    stage(cur ^ 1, k0);
    compute(cur);
    __syncthreads();
    cur ^= 1;
  }
  compute(cur);

  #pragma unroll
  for (int i = 0; i < 4; i++){
    int rowb = m0 + i*16 + (lane >> 4)*4;
    #pragma unroll
    for (int j = 0; j < 4; j++){
      int col = n0 + wave*64 + j*16 + lr16;
      if (col >= N) continue;
      float bv = bias0 ? bias0[col] : 0.0f;
      #pragma unroll
      for (int r2 = 0; r2 < 4; r2++){
        int row = rowb + r2;
        if (row >= M) continue;
        float v = acc[i][j][r2];
        if (skw > 1){
          ((float*)Cout)[((size_t)(blockIdx.z*M) + row)*ldc + col] = v;
          continue;
        }
        v += bv;
        if (act == 1) v = geluf(v);
        if (outbf16) ((bf16*)Cout)[(size_t)row*ldc + col] = __float2bfloat16(v);
        else         ((float*)Cout)[(size_t)row*ldc + col] = v;
      }
    }
  }
}

// ---------------- split-K reduce + epilogue (final output) ----------------
__global__ __launch_bounds__(256) void redk(
    const float* __restrict__ part, const float* __restrict__ bias,
    const float* __restrict__ resid, float* __restrict__ out,
    int M, int sk)
{
  int i = blockIdx.x*256 + threadIdx.x;
  if (i*4 >= M*768) return;
  int row = i / 192;
  int c4 = (i - row*192) * 4;
  size_t base = (size_t)row*768 + c4;
  float4 v = *(const float4*)(part + base);
  for (int z = 1; z < sk; z++){
    float4 p = *(const float4*)(part + (size_t)z*M*768 + base);
    v.x += p.x; v.y += p.y; v.z += p.z; v.w += p.w;
  }
  float4 bvec = *(const float4*)(bias + c4);
  float4 r = *(const float4*)(resid + base);
  v.x += bvec.x + r.x; v.y += bvec.y + r.y; v.z += bvec.z + r.z; v.w += bvec.w + r.w;
  *(float4*)(out + base) = v;
}

// ---------------- causal conv (D_CONV=4) + silu, both dirs ----------------
__global__ __launch_bounds__(256) void conv_kernel(
    const float* __restrict__ xz,
    const float* __restrict__ wf, const float* __restrict__ bf,
    const float* __restrict__ wb, const float* __restrict__ bb,
    bf16* __restrict__ xcf, bf16* __restrict__ xcb)
{
  int g = blockIdx.x*256 + threadIdx.x;
  if (g >= NSEQ*DM) return;
  int s = g / DM, d = g % DM;
  float xr[8];
  #pragma unroll
  for (int j = 0; j < 8; j++) xr[j] = xz[(size_t)(s*8 + j)*1536 + d];
  float wfv[4], wbv[4];
  #pragma unroll
  for (int k = 0; k < 4; k++){ wfv[k] = wf[d*4+k]; wbv[k] = wb[d*4+k]; }
  float bfv = bf[d], bbv = bb[d];
  #pragma unroll
  for (int l = 0; l < 8; l++) {
    float af = bfv, ab = bbv;
    #pragma unroll
    for (int k = 0; k < 4; k++) {
      if (l + k >= 3) {
        af += wfv[k] * xr[l + k - 3];
        ab += wbv[k] * xr[10 - l - k];
      }
    }
    xcf[(size_t)(s*8 + l)*DM + d] = __float2bfloat16(silu_fast(af));
    xcb[(size_t)(s*8 + l)*DM + d] = __float2bfloat16(silu_fast(ab));
  }
}

// ---------------- SSM scan (both dirs fused, fast-exp, staged B/C) ----------------
__global__ __launch_bounds__(256) void ssm_kernel(
    const float* __restrict__ xz,
    const bf16* __restrict__ xcf, const bf16* __restrict__ xcb,
    const bf16* __restrict__ dblf, const bf16* __restrict__ dblb,
    const bf16* __restrict__ dlf, const bf16* __restrict__ dlb,
    const float* __restrict__ Alogf, const float* __restrict__ Df,
    const float* __restrict__ Alogb, const float* __restrict__ Db,
    bf16* __restrict__ y)
{
  int s = blockIdx.y;
  int d = blockIdx.x*256 + threadIdx.x;
  int tid = threadIdx.x;
  __shared__ float sBC[2][8][32];
  #pragma unroll
  for (int i = 0; i < 2; i++){
    int idx = tid + i*256;
    int dir = idx >> 8, r = idx & 255, l = r >> 5, j = r & 31;
    const bf16* p = dir ? dblb : dblf;
    sBC[dir][l][j] = __bfloat162float(p[(size_t)(s*8 + l)*80 + 48 + j]);
  }
  float Af[NSTATE], Ab[NSTATE];
  #pragma unroll
  for (int n = 0; n < NSTATE; n++) {
    Af[n] = -__expf(Alogf[d*NSTATE + n]);
    Ab[n] = -__expf(Alogb[d*NSTATE + n]);
  }
  float Dfv = Df[d], Dbv = Db[d];
  __syncthreads();

  float hf[NSTATE] = {}, hb[NSTATE] = {};
  float yf[8], yb[8];
  #pragma unroll
  for (int l = 0; l < 8; l++) {
    int t = s*8 + l;
    float delf = __bfloat162float(dlf[(size_t)t*DM + d]);
    float uf   = __bfloat162float(xcf[(size_t)t*DM + d]);
    float duf  = delf * uf;
    float accf = 0.0f;
    #pragma unroll
    for (int n = 0; n < NSTATE; n++) {
      hf[n] = __expf(delf*Af[n])*hf[n] + duf*sBC[0][l][n];
      accf += hf[n]*sBC[0][l][16+n];
    }
    yf[l] = accf + uf*Dfv;
    float delb = __bfloat162float(dlb[(size_t)t*DM + d]);
    float ub   = __bfloat162float(xcb[(size_t)t*DM + d]);
    float dub  = delb * ub;
    float accb = 0.0f;
    #pragma unroll
    for (int n = 0; n < NSTATE; n++) {
      hb[n] = __expf(delb*Ab[n])*hb[n] + dub*sBC[1][l][n];
      accb += hb[n]*sBC[1][l][16+n];
    }
    yb[7-l] = accb + ub*Dbv;
  }
  #pragma unroll
  for (int l = 0; l < 8; l++) {
    int t = s*8 + l;
    float zv = xz[(size_t)t*1536 + DM + d];
    y[(size_t)t*DM + d] = __float2bfloat16((yf[l] + yb[l]) * silu_fast(zv));
  }
}

// ---------------- 16x16 attention over (b,f) slots, batched (pos, head) ----------------
__global__ __launch_bounds__(256) void attn_kernel(
    const bf16* __restrict__ qkv, bf16* __restrict__ ao)
{
  int n = blockIdx.x / 12, h = blockIdx.x % 12;
  __shared__ float qs[16][65], ks[16][65], vs[16][65], ps[16][17];
  int tid = threadIdx.x;
  for (int e = tid; e < 1024; e += 256) {
    int l = e >> 6, c = e & 63;
    size_t row = ((size_t)l*197 + n)*2304 + h*64 + c;
    qs[l][c] = __bfloat162float(qkv[row]);
    ks[l][c] = __bfloat162float(qkv[row + 768]);
    vs[l][c] = __bfloat162float(qkv[row + 1536]);
  }
  __syncthreads();
  int l = tid >> 4, m = tid & 15;
  float sc = 0.0f;
  #pragma unroll
  for (int c = 0; c < 64; c++) sc += qs[l][c]*ks[m][c];
  sc *= 0.125f;
  float mx = sc;
  #pragma unroll
  for (int o = 8; o > 0; o >>= 1) mx = fmaxf(mx, __shfl_xor(mx, o, 16));
  float p = __expf(sc - mx);
  float smv = p;
  #pragma unroll
  for (int o = 8; o > 0; o >>= 1) smv += __shfl_xor(smv, o, 16);
  ps[l][m] = __fdividef(p, smv);
  __syncthreads();
  for (int e = tid; e < 1024; e += 256) {
    int ll = e >> 6, c = e & 63;
    float acc = 0.0f;
    #pragma unroll
    for (int mm = 0; mm < 16; mm++) acc += ps[ll][mm]*vs[mm][c];
    ao[((size_t)ll*197 + n)*768 + h*64 + c] = __float2bfloat16(acc);
  }
}

extern "C" void kernel_launch(void* const* d_in, const int* in_sizes, int n_in,
                              void* d_out, int out_size, void* d_ws, size_t ws_size,
                              hipStream_t stream) {
  const float* x        = (const float*)d_in[0];
  const float* norm1_w  = (const float*)d_in[1];
  const float* norm1_b  = (const float*)d_in[2];
  const float* norm2_w  = (const float*)d_in[3];
  const float* norm2_b  = (const float*)d_in[4];
  const float* norm3_w  = (const float*)d_in[5];
  const float* norm3_b  = (const float*)d_in[6];
  const float* attn_in_w  = (const float*)d_in[7];
  const float* attn_in_b  = (const float*)d_in[8];
  const float* attn_out_w = (const float*)d_in[9];
  const float* attn_out_b = (const float*)d_in[10];
  const float* m_in_w   = (const float*)d_in[11];
  const float* m_conv_w = (const float*)d_in[12];
  const float* m_conv_b = (const float*)d_in[13];
  const float* m_xproj_w= (const float*)d_in[14];
  const float* m_dt_w   = (const float*)d_in[15];
  const float* m_dt_b   = (const float*)d_in[16];
  const float* m_Alog   = (const float*)d_in[17];
  const float* m_D      = (const float*)d_in[18];
  const float* m_conv_wb= (const float*)d_in[19];
  const float* m_conv_bb= (const float*)d_in[20];
  const float* m_xproj_wb=(const float*)d_in[21];
  const float* m_dt_wb  = (const float*)d_in[22];
  const float* m_dt_bb  = (const float*)d_in[23];
  const float* m_Alog_b = (const float*)d_in[24];
  const float* m_D_b    = (const float*)d_in[25];
  const float* m_out_w  = (const float*)d_in[26];
  const float* fc1_w    = (const float*)d_in[27];
  const float* fc1_b    = (const float*)d_in[28];
  const float* fc2_w    = (const float*)d_in[29];
  const float* fc2_b    = (const float*)d_in[30];

  char* wsb = (char*)d_ws;
  bf16*  wpool  = (bf16*)(wsb + 0);                 // [0, 18284544)
  bf16*  ln3    = (bf16*)(wsb + 18284544);          // 3136x768 bf16 (reused: y, ao)
  float* xz     = (float*)(wsb + 23101440);         // 3136x1536 fp32 [ends 42369024)
  bf16*  xcf    = (bf16*)(wsb + 42369024);
  bf16*  xcb    = (bf16*)(wsb + 47185920);
  bf16*  dblf   = (bf16*)(wsb + 52002816);
  bf16*  dblb   = (bf16*)(wsb + 52504576);
  bf16*  dlf    = (bf16*)(wsb + 53006336);
  bf16*  dlb    = (bf16*)(wsb + 57823232);          // ends 62640128
  bf16*  y      = ln3;
  float* part1  = (float*)(wsb + 23101440);         // outproj partials (xz dead)
  // phase 2
  bf16*  xsln   = (bf16*)(wsb + 62640128);
  bf16*  qkv    = (bf16*)(wsb + 42369024);
  bf16*  ao     = (bf16*)(wsb + 18284544);
  float* part2  = (float*)(wsb + 42369024);         // attn-out partials (qkv dead)
  float* xnew   = (float*)(wsb + 62640128);
  // phase 3
  bf16*  ln2o   = (bf16*)(wsb + 23101440);
  bf16*  h1     = (bf16*)(wsb + 42369024);
  float* part3  = (float*)(wsb + 18284544);

  bf16* w_in  = wpool + 0;
  bf16* w_xpf = wpool + 1179648;
  bf16* w_xpb = wpool + 1277952;
  bf16* w_dtf = wpool + 1376256;
  bf16* w_dtb = wpool + 1425408;
  bf16* w_out = wpool + 1474560;
  bf16* w_qkv = wpool + 2064384;
  bf16* w_ao  = wpool + 3833856;
  bf16* w_fc1 = wpool + 4423680;
  bf16* w_fc2 = wpool + 6782976;

  const int BIGM = 1 << 30;

  cvtw_kernel<<<dim3(2304, 10), 256, 0, stream>>>(
      m_in_w, m_xproj_w, m_xproj_wb, m_dt_w, m_dt_wb, m_out_w,
      attn_in_w, attn_out_w, fc1_w, fc2_w, wpool);

  // ===== phase 1: mamba over time tokens =====
  ln_kernel<<<MT, 256, 0, stream>>>(x, norm3_w, norm3_b, ln3);
  mgemm2<<<dim3(12, 49), 128, 0, stream>>>(ln3, DM, w_in, DM,
      nullptr, xz, MT, 1536, 1536, DM, 0, 0, 1);
  conv_kernel<<<(NSEQ*DM + 255)/256, 256, 0, stream>>>(
      xz, m_conv_w, m_conv_b, m_conv_wb, m_conv_bb, xcf, xcb);
  mgemm<64,64><<<dim3(2, 98), 256, 0, stream>>>(xcf, DM, w_xpf, w_xpb, DM,
      nullptr, nullptr, dblf, 2*MT, MT, 80, 80, DM, 0, 1);
  mgemm<64,64><<<dim3(12, 98), 256, 0, stream>>>(dblf, 80, w_dtf, w_dtb, 64,
      m_dt_b, m_dt_bb, dlf, 2*MT, MT, DM, DM, 64, 2, 1);
  ssm_kernel<<<dim3(3, NSEQ), 256, 0, stream>>>(
      xz, xcf, xcb, dblf, dblb, dlf, dlb, m_Alog, m_D, m_Alog_b, m_D_b, y);
  mgemm2<<<dim3(6, 49, 2), 128, 0, stream>>>(y, DM, w_out, DM,
      nullptr, part1, MT, DM, DM, 384, 0, 0, 2);

  // ===== phase 2: attention over space =====
  redk_ln<<<AT, 256, 0, stream>>>(part1, x, norm1_w, norm1_b, xsln);
  mgemm2<<<dim3(18, 50), 128, 0, stream>>>(xsln, DM, w_qkv, DM,
      attn_in_b, qkv, AT, 2304, 2304, DM, 0, 1, 1);
  attn_kernel<<<197*12, 256, 0, stream>>>(qkv, ao);
  mgemm2<<<dim3(6, 50, 2), 128, 0, stream>>>(ao, DM, w_ao, DM,
      nullptr, part2, AT, DM, DM, 384, 0, 0, 2);

  // ===== phase 3: MLP =====
  scatter_ln<<<XTOK, 256, 0, stream>>>(part2, attn_out_b, x, xnew,
      norm2_w, norm2_b, ln2o);
  mgemm2<<<dim3(24, 50), 128, 0, stream>>>(ln2o, DM, w_fc1, DM,
      fc1_b, h1, XTOK, 3072, 3072, DM, 1, 1, 1);
  mgemm2<<<dim3(6, 50, 2), 128, 0, stream>>>(h1, 3072, w_fc2, 3072,
      nullptr, part3, XTOK, DM, DM, 1536, 0, 0, 2);
  redk<<<2354, 256, 0, stream>>>(part3, fc2_b, xnew, (float*)d_out, XTOK, 2);
}

// Round 11
// 263.729 us; speedup vs baseline: 1.1839x; 1.1839x over previous
//
#include <hip/hip_runtime.h>
#include <hip/hip_bf16.h>
#include <math.h>

#define DM 768
#define NBATCH 2
#define TIMEN 196
#define SPACEF 8
#define SEQL 1569          // 1 + 196*8
#define NSTATE 16
#define MT 3136            // mamba tokens = 2*196*8
#define NSEQ 392           // mamba sequences = 2*196, each length 8
#define AT 3152            // attn tokens = 16*197
#define XTOK 3138          // 2*1569

typedef __attribute__((ext_vector_type(8))) short s16x8;
typedef __attribute__((ext_vector_type(4))) float f32x4;
typedef __hip_bfloat16 bf16;

__device__ __forceinline__ float silu_fast(float x){ return __fdividef(x, 1.0f + __expf(-x)); }
// tanh-form GELU, overflow-safe (max err vs exact-erf gelu ~1e-3)
__device__ __forceinline__ float geluf(float x){
  float y = 0.7978845608f * (x + 0.044715f*x*x*x);
  float ay = fabsf(y);
  float e = __expf(-2.0f*ay);
  float t = __fdividef(1.0f - e, 1.0f + e);
  t = copysignf(t, y);
  return 0.5f*x*(1.0f + t);
}
__device__ __forceinline__ float softplusf(float x){
  return (x > 20.0f) ? x : __logf(1.0f + __expf(x));
}
__device__ __forceinline__ int imin(int a, int b){ return a < b ? a : b; }

#define GLD_LDS16(g, l) __builtin_amdgcn_global_load_lds( \
    (const __attribute__((address_space(1))) void*)(g), \
    (__attribute__((address_space(3))) void*)(l), 16, 0, 0)

// ---------------- block row sum helper ----------------
__device__ __forceinline__ float block_sum256(float v, float* sm){
  #pragma unroll
  for (int o = 32; o > 0; o >>= 1) v += __shfl_down(v, o);
  __syncthreads();
  if ((threadIdx.x & 63) == 0) sm[threadIdx.x >> 6] = v;
  __syncthreads();
  return sm[0] + sm[1] + sm[2] + sm[3];
}

// ---------------- weight fp32 -> padded bf16 pool ----------------
template<int N, int K, int Np, int Kp>
__device__ __forceinline__ void cvt_seg(const float* __restrict__ src, bf16* __restrict__ dst){
  const int total = Np * Kp;
  int base = blockIdx.x * 1024 + threadIdx.x;
  #pragma unroll
  for (int e = 0; e < 4; e++){
    int idx = base + e * 256;
    if (idx < total){
      int n = idx / Kp, k = idx % Kp;
      float v = (n < N && k < K) ? src[n * K + k] : 0.0f;
      dst[idx] = __float2bfloat16(v);
    }
  }
}

// y<10: weight convert segments; y==10: LN3 over xt gather
__global__ __launch_bounds__(256) void prep_kernel(
    const float* s0, const float* s1, const float* s2, const float* s3,
    const float* s4, const float* s5, const float* s6, const float* s7,
    const float* s8, const float* s9, bf16* w,
    const float* __restrict__ x, const float* __restrict__ ln3w,
    const float* __restrict__ ln3b, bf16* __restrict__ ln3o)
{
  switch (blockIdx.y) {
    case 0: cvt_seg<1536,768,1536,768>(s0, w + 0);        break; // m_in_w
    case 1: cvt_seg<  80,768, 128,768>(s1, w + 1179648);  break; // xproj f
    case 2: cvt_seg<  80,768, 128,768>(s2, w + 1277952);  break; // xproj b
    case 3: cvt_seg< 768, 48, 768, 64>(s3, w + 1376256);  break; // dt f (K zero-pad)
    case 4: cvt_seg< 768, 48, 768, 64>(s4, w + 1425408);  break; // dt b
    case 5: cvt_seg< 768,768, 768,768>(s5, w + 1474560);  break; // m_out_w
    case 6: cvt_seg<2304,768,2304,768>(s6, w + 2064384);  break; // attn_in_w
    case 7: cvt_seg< 768,768, 768,768>(s7, w + 3833856);  break; // attn_out_w
    case 8: cvt_seg<3072,768,3072,768>(s8, w + 4423680);  break; // fc1
    case 9: cvt_seg< 768,3072,768,3072>(s9, w + 6782976); break; // fc2
    default: {
      __shared__ float sm[4];
      int tok = blockIdx.x;
      if (tok >= MT) return;
      int bi = tok / (TIMEN*SPACEF), r = tok % (TIMEN*SPACEF);
      const float* src = x + ((size_t)bi * SEQL + 1 + r) * DM;
      int tid = threadIdx.x;
      float xr[3];
      #pragma unroll
      for (int i = 0; i < 3; i++) xr[i] = src[tid + i*256];
      float mean = block_sum256(xr[0]+xr[1]+xr[2], sm) * (1.0f/768.0f);
      float v0 = xr[0]-mean, v1 = xr[1]-mean, v2 = xr[2]-mean;
      float var = block_sum256(v0*v0 + v1*v1 + v2*v2, sm) * (1.0f/768.0f);
      float rstd = rsqrtf(var + 1e-5f);
      bf16* o = ln3o + (size_t)tok * DM;
      #pragma unroll
      for (int i = 0; i < 3; i++){ int c = tid + i*256;
        o[c] = __float2bfloat16((xr[i]-mean)*rstd*ln3w[c] + ln3b[c]); }
    }
  }
}

// ---------------- fused out-proj reduce + LN1 (xs gather) -> xsln bf16 ----------------
__global__ __launch_bounds__(256) void redk_ln(
    const float* __restrict__ part, const float* __restrict__ x,
    const float* __restrict__ w, const float* __restrict__ b,
    bf16* __restrict__ out)
{
  __shared__ float sm[4];
  int tok = blockIdx.x;
  int sidx = tok / 197, p = tok % 197;
  int tid = threadIdx.x;
  float xr[3];
  if (p == 0) {
    const float* src = x + (size_t)(sidx >> 3) * SEQL * DM;
    #pragma unroll
    for (int i = 0; i < 3; i++) xr[i] = src[tid + i*256];
  } else {
    int bi = sidx >> 3, f = sidx & 7, t = p - 1;
    size_t mt = ((size_t)(bi*TIMEN + t))*SPACEF + f;
    const float* p0 = part + mt*DM;
    const float* p1 = part + ((size_t)MT + mt)*DM;
    const float* xs = x + ((size_t)bi*SEQL + 1 + t*SPACEF + f)*DM;
    #pragma unroll
    for (int i = 0; i < 3; i++){ int c = tid + i*256;
      xr[i] = p0[c] + p1[c] + xs[c]; }
  }
  float mean = block_sum256(xr[0]+xr[1]+xr[2], sm) * (1.0f/768.0f);
  float v0 = xr[0]-mean, v1 = xr[1]-mean, v2 = xr[2]-mean;
  float var = block_sum256(v0*v0 + v1*v1 + v2*v2, sm) * (1.0f/768.0f);
  float rstd = rsqrtf(var + 1e-5f);
  bf16* o = out + (size_t)tok * DM;
  #pragma unroll
  for (int i = 0; i < 3; i++){ int c = tid + i*256;
    o[c] = __float2bfloat16((xr[i]-mean)*rstd*w[c] + b[c]); }
}

// ---------------- fused attn-out reduce + scatter + LN2 ----------------
__global__ __launch_bounds__(256) void scatter_ln(
    const float* __restrict__ part, const float* __restrict__ bias,
    const float* __restrict__ x, float* __restrict__ xnew,
    const float* __restrict__ w, const float* __restrict__ b,
    bf16* __restrict__ out)
{
  __shared__ float sm[4];
  int tok = blockIdx.x;
  int bi = tok / SEQL, row = tok % SEQL;
  int tid = threadIdx.x;
  const float* p1 = part + (size_t)AT*DM;
  const float* xs = x + (size_t)tok*DM;
  float xr[3];
  if (row == 0) {
    #pragma unroll
    for (int i = 0; i < 3; i++){ int c = tid + i*256;
      float acc = 0.0f;
      #pragma unroll
      for (int f = 0; f < SPACEF; f++){
        size_t r = ((size_t)(bi*SPACEF + f)*197)*DM + c;
        acc += part[r] + p1[r];
      }
      xr[i] = xs[c] + acc * 0.125f + bias[c];
    }
  } else {
    int t = (row - 1) >> 3, f = (row - 1) & 7;
    size_t r = ((size_t)((bi*SPACEF + f)*197) + 1 + t)*DM;
    #pragma unroll
    for (int i = 0; i < 3; i++){ int c = tid + i*256;
      xr[i] = xs[c] + part[r + c] + p1[r + c] + bias[c];
    }
  }
  float* xo = xnew + (size_t)tok*DM;
  #pragma unroll
  for (int i = 0; i < 3; i++) xo[tid + i*256] = xr[i];
  float mean = block_sum256(xr[0]+xr[1]+xr[2], sm) * (1.0f/768.0f);
  float v0 = xr[0]-mean, v1 = xr[1]-mean, v2 = xr[2]-mean;
  float var = block_sum256(v0*v0 + v1*v1 + v2*v2, sm) * (1.0f/768.0f);
  float rstd = rsqrtf(var + 1e-5f);
  bf16* o = out + (size_t)tok*DM;
  #pragma unroll
  for (int i = 0; i < 3; i++){ int c = tid + i*256;
    o[c] = __float2bfloat16((xr[i]-mean)*rstd*w[c] + b[c]); }
}

// ======= 4-wave 64x64 BK=64 GEMM, swizzled LDS, 2-phase dbuf, split-K =======
// skw==1: C = act(A @ Wsel^T + bias_sel)  (Wsel = m0<mhalf ? W0 : W1)
// skw>1 : fp32 partial at Cout[(z*M + row)*ldc + col]; K slice = KP, offset z*KP
template<int BM, int BN>
__global__ __launch_bounds__(256) void mgemm(
    const bf16* __restrict__ A, int lda,
    const bf16* __restrict__ W0, const bf16* __restrict__ W1, int ldw,
    const float* __restrict__ bias0, const float* __restrict__ bias1,
    void* __restrict__ Cout, int M, int mhalf, int N, int ldc, int KP,
    int act, int outbf16, int skw)
{
  constexpr int WM = BM/2, WN = BN/2, MI = WM/16, NJ = WN/16;
  __shared__ bf16 As[2][BM*64];
  __shared__ bf16 Bs[2][BN*64];
  int tid = threadIdx.x;
  int wave = tid >> 6, lane = tid & 63;

  // XCD-aware block placement. Assumes bid%8 round-robins XCDs.
  int gx = gridDim.x, gy = gridDim.y;
  int nwg = gx * gy;
  int bid = blockIdx.y * gx + blockIdx.x;
  int m0, n0;
  if ((gx & 3) == 0 && (gy & 1) == 0) {
    // 2D: each XCD owns a (gy/2) x (gx/4) rectangle
    int cw = gx >> 2, rh = gy >> 1;
    int xcd = bid & 7, lidx = bid >> 3;
    int rx = xcd & 3, ry = xcd >> 2;
    m0 = ((ry * rh) + lidx / cw) * BM;
    n0 = ((rx * cw) + lidx % cw) * BN;
  } else {
    // bijective linear chunk (cols fastest)
    int q = nwg >> 3, r = nwg & 7;
    int xcd = bid & 7, lidx = bid >> 3;
    int wg = (xcd < r ? xcd*(q+1) : r*(q+1) + (xcd-r)*q) + lidx;
    m0 = (wg / gx) * BM; n0 = (wg % gx) * BN;
  }

  int wr = wave >> 1, wc = wave & 1;

  int koff = blockIdx.z * KP;
  const bf16* Ak = A + koff;
  const bf16* Wt = ((m0 < mhalf) ? W0 : W1) + koff;
  const float* bias = (m0 < mhalf) ? bias0 : bias1;

  f32x4 acc[MI][NJ];
  #pragma unroll
  for (int i = 0; i < MI; i++)
    #pragma unroll
    for (int j = 0; j < NJ; j++) acc[i][j] = (f32x4){0.f,0.f,0.f,0.f};

  // staging: 8 rows x 128B per gld; source col pre-swizzled so linear LDS dest
  // equals swizzled layout (lds col block = (l&7)^(row&7)); read XORs it back.
  int sr8 = lane >> 3;
  int scs = (((lane & 7) ^ sr8) * 8);
  int lr16 = lane & 15, ks = (lane >> 4) * 8;
  int swz = (lr16 & 7) << 3;

  auto stage = [&](int buf, int k0){
    #pragma unroll
    for (int g = 0; g < BM/32; g++){
      int rr = wave*(BM/4) + g*8;
      const bf16* ga = Ak + (size_t)imin(m0 + rr + sr8, M-1)*lda + k0 + scs;
      GLD_LDS16(ga, &As[buf][rr*64]);
    }
    #pragma unroll
    for (int g = 0; g < BN/32; g++){
      int rr = wave*(BN/4) + g*8;
      const bf16* gb = Wt + (size_t)(n0 + rr + sr8)*ldw + k0 + scs;
      GLD_LDS16(gb, &Bs[buf][rr*64]);
    }
  };

  auto compute = [&](int buf){
    s16x8 afr[2][MI], bfr[2][NJ];
    #pragma unroll
    for (int kk = 0; kk < 2; kk++){
      #pragma unroll
      for (int i = 0; i < MI; i++)
        afr[kk][i] = *(const s16x8*)&As[buf][(wr*WM + i*16 + lr16)*64 + ((kk*32 + ks) ^ swz)];
      #pragma unroll
      for (int j = 0; j < NJ; j++)
        bfr[kk][j] = *(const s16x8*)&Bs[buf][(wc*WN + j*16 + lr16)*64 + ((kk*32 + ks) ^ swz)];
    }
    #pragma unroll
    for (int kk = 0; kk < 2; kk++)
      #pragma unroll
      for (int i = 0; i < MI; i++)
        #pragma unroll
        for (int j = 0; j < NJ; j++)
          acc[i][j] = __builtin_amdgcn_mfma_f32_16x16x32_bf16(afr[kk][i], bfr[kk][j], acc[i][j], 0, 0, 0);
  };

  stage(0, 0);
  __syncthreads();
  int cur = 0;
  for (int k0 = 64; k0 < KP; k0 += 64){
    stage(cur ^ 1, k0);
    compute(cur);
    __syncthreads();
    cur ^= 1;
  }
  compute(cur);

  #pragma unroll
  for (int i = 0; i < MI; i++){
    int rowb = m0 + wr*WM + i*16 + (lane >> 4)*4;
    #pragma unroll
    for (int j = 0; j < NJ; j++){
      int col = n0 + wc*WN + j*16 + lr16;
      if (col >= N) continue;
      float bv = bias ? bias[col] : 0.0f;
      #pragma unroll
      for (int r2 = 0; r2 < 4; r2++){
        int row = rowb + r2;
        if (row >= M) continue;
        float v = acc[i][j][r2];
        if (skw > 1){
          ((float*)Cout)[((size_t)(blockIdx.z*M) + row)*ldc + col] = v;
          continue;
        }
        v += bv;
        if (act == 1) v = geluf(v);
        else if (act == 2) v = softplusf(v);
        if (outbf16) ((bf16*)Cout)[(size_t)row*ldc + col] = __float2bfloat16(v);
        else         ((float*)Cout)[(size_t)row*ldc + col] = v;
      }
    }
  }
}

// ---------------- split-K reduce + epilogue (final output) ----------------
__global__ __launch_bounds__(256) void redk(
    const float* __restrict__ part, const float* __restrict__ bias,
    const float* __restrict__ resid, float* __restrict__ out,
    int M, int sk)
{
  int i = blockIdx.x*256 + threadIdx.x;
  if (i*4 >= M*768) return;
  int row = i / 192;
  int c4 = (i - row*192) * 4;
  size_t base = (size_t)row*768 + c4;
  float4 v = *(const float4*)(part + base);
  for (int z = 1; z < sk; z++){
    float4 p = *(const float4*)(part + (size_t)z*M*768 + base);
    v.x += p.x; v.y += p.y; v.z += p.z; v.w += p.w;
  }
  float4 bvec = *(const float4*)(bias + c4);
  float4 r = *(const float4*)(resid + base);
  v.x += bvec.x + r.x; v.y += bvec.y + r.y; v.z += bvec.z + r.z; v.w += bvec.w + r.w;
  *(float4*)(out + base) = v;
}

// ---------------- causal conv (D_CONV=4) + silu, both dirs (bf16 xz) ----------------
__global__ __launch_bounds__(256) void conv_kernel(
    const bf16* __restrict__ xz,
    const float* __restrict__ wf, const float* __restrict__ bf,
    const float* __restrict__ wb, const float* __restrict__ bb,
    bf16* __restrict__ xcf, bf16* __restrict__ xcb)
{
  int g = blockIdx.x*256 + threadIdx.x;
  if (g >= NSEQ*DM) return;
  int s = g / DM, d = g % DM;
  float xr[8];
  #pragma unroll
  for (int j = 0; j < 8; j++) xr[j] = __bfloat162float(xz[(size_t)(s*8 + j)*1536 + d]);
  float wfv[4], wbv[4];
  #pragma unroll
  for (int k = 0; k < 4; k++){ wfv[k] = wf[d*4+k]; wbv[k] = wb[d*4+k]; }
  float bfv = bf[d], bbv = bb[d];
  #pragma unroll
  for (int l = 0; l < 8; l++) {
    float af = bfv, ab = bbv;
    #pragma unroll
    for (int k = 0; k < 4; k++) {
      if (l + k >= 3) {
        af += wfv[k] * xr[l + k - 3];
        ab += wbv[k] * xr[10 - l - k];
      }
    }
    xcf[(size_t)(s*8 + l)*DM + d] = __float2bfloat16(silu_fast(af));
    xcb[(size_t)(s*8 + l)*DM + d] = __float2bfloat16(silu_fast(ab));
  }
}

// ---------------- SSM scan (both dirs fused, fast-exp, staged B/C) ----------------
__global__ __launch_bounds__(256) void ssm_kernel(
    const bf16* __restrict__ xz,
    const bf16* __restrict__ xcf, const bf16* __restrict__ xcb,
    const bf16* __restrict__ dblf, const bf16* __restrict__ dblb,
    const bf16* __restrict__ dlf, const bf16* __restrict__ dlb,
    const float* __restrict__ Alogf, const float* __restrict__ Df,
    const float* __restrict__ Alogb, const float* __restrict__ Db,
    bf16* __restrict__ y)
{
  int s = blockIdx.y;
  int d = blockIdx.x*256 + threadIdx.x;
  int tid = threadIdx.x;
  __shared__ float sBC[2][8][32];
  #pragma unroll
  for (int i = 0; i < 2; i++){
    int idx = tid + i*256;
    int dir = idx >> 8, r = idx & 255, l = r >> 5, j = r & 31;
    const bf16* p = dir ? dblb : dblf;
    sBC[dir][l][j] = __bfloat162float(p[(size_t)(s*8 + l)*80 + 48 + j]);
  }
  float Af[NSTATE], Ab[NSTATE];
  #pragma unroll
  for (int n = 0; n < NSTATE; n++) {
    Af[n] = -__expf(Alogf[d*NSTATE + n]);
    Ab[n] = -__expf(Alogb[d*NSTATE + n]);
  }
  float Dfv = Df[d], Dbv = Db[d];
  __syncthreads();

  float hf[NSTATE] = {}, hb[NSTATE] = {};
  float yf[8], yb[8];
  #pragma unroll
  for (int l = 0; l < 8; l++) {
    int t = s*8 + l;
    float delf = __bfloat162float(dlf[(size_t)t*DM + d]);
    float uf   = __bfloat162float(xcf[(size_t)t*DM + d]);
    float duf  = delf * uf;
    float accf = 0.0f;
    #pragma unroll
    for (int n = 0; n < NSTATE; n++) {
      hf[n] = __expf(delf*Af[n])*hf[n] + duf*sBC[0][l][n];
      accf += hf[n]*sBC[0][l][16+n];
    }
    yf[l] = accf + uf*Dfv;
    float delb = __bfloat162float(dlb[(size_t)t*DM + d]);
    float ub   = __bfloat162float(xcb[(size_t)t*DM + d]);
    float dub  = delb * ub;
    float accb = 0.0f;
    #pragma unroll
    for (int n = 0; n < NSTATE; n++) {
      hb[n] = __expf(delb*Ab[n])*hb[n] + dub*sBC[1][l][n];
      accb += hb[n]*sBC[1][l][16+n];
    }
    yb[7-l] = accb + ub*Dbv;
  }
  #pragma unroll
  for (int l = 0; l < 8; l++) {
    int t = s*8 + l;
    float zv = __bfloat162float(xz[(size_t)t*1536 + DM + d]);
    y[(size_t)t*DM + d] = __float2bfloat16((yf[l] + yb[l]) * silu_fast(zv));
  }
}

// ---------------- 16x16 attention over (b,f) slots, batched (pos, head) ----------------
__global__ __launch_bounds__(256) void attn_kernel(
    const bf16* __restrict__ qkv, bf16* __restrict__ ao)
{
  int n = blockIdx.x / 12, h = blockIdx.x % 12;
  __shared__ float qs[16][65], ks[16][65], vs[16][65], ps[16][17];
  int tid = threadIdx.x;
  for (int e = tid; e < 1024; e += 256) {
    int l = e >> 6, c = e & 63;
    size_t row = ((size_t)l*197 + n)*2304 + h*64 + c;
    qs[l][c] = __bfloat162float(qkv[row]);
    ks[l][c] = __bfloat162float(qkv[row + 768]);
    vs[l][c] = __bfloat162float(qkv[row + 1536]);
  }
  __syncthreads();
  int l = tid >> 4, m = tid & 15;
  float sc = 0.0f;
  #pragma unroll
  for (int c = 0; c < 64; c++) sc += qs[l][c]*ks[m][c];
  sc *= 0.125f;
  float mx = sc;
  #pragma unroll
  for (int o = 8; o > 0; o >>= 1) mx = fmaxf(mx, __shfl_xor(mx, o, 16));
  float p = __expf(sc - mx);
  float smv = p;
  #pragma unroll
  for (int o = 8; o > 0; o >>= 1) smv += __shfl_xor(smv, o, 16);
  ps[l][m] = __fdividef(p, smv);
  __syncthreads();
  for (int e = tid; e < 1024; e += 256) {
    int ll = e >> 6, c = e & 63;
    float acc = 0.0f;
    #pragma unroll
    for (int mm = 0; mm < 16; mm++) acc += ps[ll][mm]*vs[mm][c];
    ao[((size_t)ll*197 + n)*768 + h*64 + c] = __float2bfloat16(acc);
  }
}

extern "C" void kernel_launch(void* const* d_in, const int* in_sizes, int n_in,
                              void* d_out, int out_size, void* d_ws, size_t ws_size,
                              hipStream_t stream) {
  const float* x        = (const float*)d_in[0];
  const float* norm1_w  = (const float*)d_in[1];
  const float* norm1_b  = (const float*)d_in[2];
  const float* norm2_w  = (const float*)d_in[3];
  const float* norm2_b  = (const float*)d_in[4];
  const float* norm3_w  = (const float*)d_in[5];
  const float* norm3_b  = (const float*)d_in[6];
  const float* attn_in_w  = (const float*)d_in[7];
  const float* attn_in_b  = (const float*)d_in[8];
  const float* attn_out_w = (const float*)d_in[9];
  const float* attn_out_b = (const float*)d_in[10];
  const float* m_in_w   = (const float*)d_in[11];
  const float* m_conv_w = (const float*)d_in[12];
  const float* m_conv_b = (const float*)d_in[13];
  const float* m_xproj_w= (const float*)d_in[14];
  const float* m_dt_w   = (const float*)d_in[15];
  const float* m_dt_b   = (const float*)d_in[16];
  const float* m_Alog   = (const float*)d_in[17];
  const float* m_D      = (const float*)d_in[18];
  const float* m_conv_wb= (const float*)d_in[19];
  const float* m_conv_bb= (const float*)d_in[20];
  const float* m_xproj_wb=(const float*)d_in[21];
  const float* m_dt_wb  = (const float*)d_in[22];
  const float* m_dt_bb  = (const float*)d_in[23];
  const float* m_Alog_b = (const float*)d_in[24];
  const float* m_D_b    = (const float*)d_in[25];
  const float* m_out_w  = (const float*)d_in[26];
  const float* fc1_w    = (const float*)d_in[27];
  const float* fc1_b    = (const float*)d_in[28];
  const float* fc2_w    = (const float*)d_in[29];
  const float* fc2_b    = (const float*)d_in[30];

  char* wsb = (char*)d_ws;
  bf16*  wpool  = (bf16*)(wsb + 0);                 // [0, 18284544)
  bf16*  ln3    = (bf16*)(wsb + 18284544);          // 3136x768 bf16 (reused: y, ao)
  bf16*  xz     = (bf16*)(wsb + 23101440);          // 3136x1536 bf16 (9.63MB)
  bf16*  xcf    = (bf16*)(wsb + 42369024);
  bf16*  xcb    = (bf16*)(wsb + 47185920);
  bf16*  dblf   = (bf16*)(wsb + 52002816);
  bf16*  dblb   = (bf16*)(wsb + 52504576);
  bf16*  dlf    = (bf16*)(wsb + 53006336);
  bf16*  dlb    = (bf16*)(wsb + 57823232);          // ends 62640128
  bf16*  y      = ln3;
  float* part1  = (float*)(wsb + 23101440);         // outproj partials (xz dead after ssm)
  // phase 2
  bf16*  xsln   = (bf16*)(wsb + 62640128);
  bf16*  qkv    = (bf16*)(wsb + 42369024);
  bf16*  ao     = (bf16*)(wsb + 18284544);
  float* part2  = (float*)(wsb + 42369024);         // attn-out partials (qkv dead)
  float* xnew   = (float*)(wsb + 62640128);
  // phase 3
  bf16*  ln2o   = (bf16*)(wsb + 23101440);
  bf16*  h1     = (bf16*)(wsb + 42369024);
  float* part3  = (float*)(wsb + 18284544);

  bf16* w_in  = wpool + 0;
  bf16* w_xpf = wpool + 1179648;
  bf16* w_xpb = wpool + 1277952;
  bf16* w_dtf = wpool + 1376256;
  bf16* w_dtb = wpool + 1425408;
  bf16* w_out = wpool + 1474560;
  bf16* w_qkv = wpool + 2064384;
  bf16* w_ao  = wpool + 3833856;
  bf16* w_fc1 = wpool + 4423680;
  bf16* w_fc2 = wpool + 6782976;

  const int BIGM = 1 << 30;

  // weight convert + LN3 in one launch
  prep_kernel<<<dim3(3136, 11), 256, 0, stream>>>(
      m_in_w, m_xproj_w, m_xproj_wb, m_dt_w, m_dt_wb, m_out_w,
      attn_in_w, attn_out_w, fc1_w, fc2_w, wpool,
      x, norm3_w, norm3_b, ln3);

  // ===== phase 1: mamba over time tokens =====
  mgemm<64,64><<<dim3(24, 49), 256, 0, stream>>>(ln3, DM, w_in, w_in, DM,
      nullptr, nullptr, xz, MT, BIGM, 1536, 1536, DM, 0, 1, 1);
  conv_kernel<<<(NSEQ*DM + 255)/256, 256, 0, stream>>>(
      xz, m_conv_w, m_conv_b, m_conv_wb, m_conv_bb, xcf, xcb);
  mgemm<64,64><<<dim3(2, 98), 256, 0, stream>>>(xcf, DM, w_xpf, w_xpb, DM,
      nullptr, nullptr, dblf, 2*MT, MT, 80, 80, DM, 0, 1, 1);
  mgemm<64,64><<<dim3(12, 98), 256, 0, stream>>>(dblf, 80, w_dtf, w_dtb, 64,
      m_dt_b, m_dt_bb, dlf, 2*MT, MT, DM, DM, 64, 2, 1, 1);
  ssm_kernel<<<dim3(3, NSEQ), 256, 0, stream>>>(
      xz, xcf, xcb, dblf, dblb, dlf, dlb, m_Alog, m_D, m_Alog_b, m_D_b, y);
  mgemm<64,64><<<dim3(12, 49, 2), 256, 0, stream>>>(y, DM, w_out, w_out, DM,
      nullptr, nullptr, part1, MT, BIGM, DM, DM, 384, 0, 0, 2);

  // ===== phase 2: attention over space =====
  redk_ln<<<AT, 256, 0, stream>>>(part1, x, norm1_w, norm1_b, xsln);
  mgemm<64,64><<<dim3(36, 50), 256, 0, stream>>>(xsln, DM, w_qkv, w_qkv, DM,
      attn_in_b, attn_in_b, qkv, AT, BIGM, 2304, 2304, DM, 0, 1, 1);
  attn_kernel<<<197*12, 256, 0, stream>>>(qkv, ao);
  mgemm<64,64><<<dim3(12, 50, 2), 256, 0, stream>>>(ao, DM, w_ao, w_ao, DM,
      nullptr, nullptr, part2, AT, BIGM, DM, DM, 384, 0, 0, 2);

  // ===== phase 3: MLP =====
  scatter_ln<<<XTOK, 256, 0, stream>>>(part2, attn_out_b, x, xnew,
      norm2_w, norm2_b, ln2o);
  mgemm<64,64><<<dim3(48, 50), 256, 0, stream>>>(ln2o, DM, w_fc1, w_fc1, DM,
      fc1_b, fc1_b, h1, XTOK, BIGM, 3072, 3072, DM, 1, 1, 1);
  mgemm<64,64><<<dim3(12, 50, 2), 256, 0, stream>>>(h1, 3072, w_fc2, w_fc2, 3072,
      nullptr, nullptr, part3, XTOK, BIGM, DM, DM, 1536, 0, 0, 2);
  redk<<<2354, 256, 0, stream>>>(part3, fc2_b, xnew, (float*)d_out, XTOK, 2);
}

// Round 12
// 261.979 us; speedup vs baseline: 1.1919x; 1.0067x over previous
//
#include <hip/hip_runtime.h>
#include <hip/hip_bf16.h>
#include <math.h>

#define DM 768
#define NBATCH 2
#define TIMEN 196
#define SPACEF 8
#define SEQL 1569          // 1 + 196*8
#define NSTATE 16
#define MT 3136            // mamba tokens = 2*196*8
#define NSEQ 392           // mamba sequences = 2*196, each length 8
#define AT 3152            // attn tokens = 16*197
#define XTOK 3138          // 2*1569

typedef __attribute__((ext_vector_type(8))) short s16x8;
typedef __attribute__((ext_vector_type(4))) float f32x4;
typedef __hip_bfloat16 bf16;

__device__ __forceinline__ float silu_fast(float x){ return __fdividef(x, 1.0f + __expf(-x)); }
// tanh-form GELU, overflow-safe (max err vs exact-erf gelu ~1e-3)
__device__ __forceinline__ float geluf(float x){
  float y = 0.7978845608f * (x + 0.044715f*x*x*x);
  float ay = fabsf(y);
  float e = __expf(-2.0f*ay);
  float t = __fdividef(1.0f - e, 1.0f + e);
  t = copysignf(t, y);
  return 0.5f*x*(1.0f + t);
}
__device__ __forceinline__ float softplusf(float x){
  return (x > 20.0f) ? x : __logf(1.0f + __expf(x));
}
__device__ __forceinline__ int imin(int a, int b){ return a < b ? a : b; }

#define GLD_LDS16(g, l) __builtin_amdgcn_global_load_lds( \
    (const __attribute__((address_space(1))) void*)(g), \
    (__attribute__((address_space(3))) void*)(l), 16, 0, 0)

// ---------------- block row sum helper ----------------
__device__ __forceinline__ float block_sum256(float v, float* sm){
  #pragma unroll
  for (int o = 32; o > 0; o >>= 1) v += __shfl_down(v, o);
  __syncthreads();
  if ((threadIdx.x & 63) == 0) sm[threadIdx.x >> 6] = v;
  __syncthreads();
  return sm[0] + sm[1] + sm[2] + sm[3];
}

// ---------------- weight fp32 -> padded bf16 pool ----------------
template<int N, int K, int Np, int Kp>
__device__ __forceinline__ void cvt_seg(const float* __restrict__ src, bf16* __restrict__ dst){
  const int total = Np * Kp;
  int base = blockIdx.x * 1024 + threadIdx.x;
  #pragma unroll
  for (int e = 0; e < 4; e++){
    int idx = base + e * 256;
    if (idx < total){
      int n = idx / Kp, k = idx % Kp;
      float v = (n < N && k < K) ? src[n * K + k] : 0.0f;
      dst[idx] = __float2bfloat16(v);
    }
  }
}

// y<10: weight convert segments; y==10: LN3 over xt gather
__global__ __launch_bounds__(256) void prep_kernel(
    const float* s0, const float* s1, const float* s2, const float* s3,
    const float* s4, const float* s5, const float* s6, const float* s7,
    const float* s8, const float* s9, bf16* w,
    const float* __restrict__ x, const float* __restrict__ ln3w,
    const float* __restrict__ ln3b, bf16* __restrict__ ln3o)
{
  switch (blockIdx.y) {
    case 0: cvt_seg<1536,768,1536,768>(s0, w + 0);        break; // m_in_w
    case 1: cvt_seg<  80,768, 128,768>(s1, w + 1179648);  break; // xproj f
    case 2: cvt_seg<  80,768, 128,768>(s2, w + 1277952);  break; // xproj b
    case 3: cvt_seg< 768, 48, 768, 64>(s3, w + 1376256);  break; // dt f (K zero-pad)
    case 4: cvt_seg< 768, 48, 768, 64>(s4, w + 1425408);  break; // dt b
    case 5: cvt_seg< 768,768, 768,768>(s5, w + 1474560);  break; // m_out_w
    case 6: cvt_seg<2304,768,2304,768>(s6, w + 2064384);  break; // attn_in_w
    case 7: cvt_seg< 768,768, 768,768>(s7, w + 3833856);  break; // attn_out_w
    case 8: cvt_seg<3072,768,3072,768>(s8, w + 4423680);  break; // fc1
    case 9: cvt_seg< 768,3072,768,3072>(s9, w + 6782976); break; // fc2
    default: {
      __shared__ float sm[4];
      int tok = blockIdx.x;
      if (tok >= MT) return;
      int bi = tok / (TIMEN*SPACEF), r = tok % (TIMEN*SPACEF);
      const float* src = x + ((size_t)bi * SEQL + 1 + r) * DM;
      int tid = threadIdx.x;
      float xr[3];
      #pragma unroll
      for (int i = 0; i < 3; i++) xr[i] = src[tid + i*256];
      float mean = block_sum256(xr[0]+xr[1]+xr[2], sm) * (1.0f/768.0f);
      float v0 = xr[0]-mean, v1 = xr[1]-mean, v2 = xr[2]-mean;
      float var = block_sum256(v0*v0 + v1*v1 + v2*v2, sm) * (1.0f/768.0f);
      float rstd = rsqrtf(var + 1e-5f);
      bf16* o = ln3o + (size_t)tok * DM;
      #pragma unroll
      for (int i = 0; i < 3; i++){ int c = tid + i*256;
        o[c] = __float2bfloat16((xr[i]-mean)*rstd*ln3w[c] + ln3b[c]); }
    }
  }
}

// ---------------- fused out-proj reduce + LN1 (xs gather) -> xsln bf16 ----------------
__global__ __launch_bounds__(256) void redk_ln(
    const float* __restrict__ part, const float* __restrict__ x,
    const float* __restrict__ w, const float* __restrict__ b,
    bf16* __restrict__ out)
{
  __shared__ float sm[4];
  int tok = blockIdx.x;
  int sidx = tok / 197, p = tok % 197;
  int tid = threadIdx.x;
  float xr[3];
  if (p == 0) {
    const float* src = x + (size_t)(sidx >> 3) * SEQL * DM;
    #pragma unroll
    for (int i = 0; i < 3; i++) xr[i] = src[tid + i*256];
  } else {
    int bi = sidx >> 3, f = sidx & 7, t = p - 1;
    size_t mt = ((size_t)(bi*TIMEN + t))*SPACEF + f;
    const float* p0 = part + mt*DM;
    const float* p1 = part + ((size_t)MT + mt)*DM;
    const float* xs = x + ((size_t)bi*SEQL + 1 + t*SPACEF + f)*DM;
    #pragma unroll
    for (int i = 0; i < 3; i++){ int c = tid + i*256;
      xr[i] = p0[c] + p1[c] + xs[c]; }
  }
  float mean = block_sum256(xr[0]+xr[1]+xr[2], sm) * (1.0f/768.0f);
  float v0 = xr[0]-mean, v1 = xr[1]-mean, v2 = xr[2]-mean;
  float var = block_sum256(v0*v0 + v1*v1 + v2*v2, sm) * (1.0f/768.0f);
  float rstd = rsqrtf(var + 1e-5f);
  bf16* o = out + (size_t)tok * DM;
  #pragma unroll
  for (int i = 0; i < 3; i++){ int c = tid + i*256;
    o[c] = __float2bfloat16((xr[i]-mean)*rstd*w[c] + b[c]); }
}

// ---------------- fused attn-out reduce + scatter + LN2 ----------------
__global__ __launch_bounds__(256) void scatter_ln(
    const float* __restrict__ part, const float* __restrict__ bias,
    const float* __restrict__ x, float* __restrict__ xnew,
    const float* __restrict__ w, const float* __restrict__ b,
    bf16* __restrict__ out)
{
  __shared__ float sm[4];
  int tok = blockIdx.x;
  int bi = tok / SEQL, row = tok % SEQL;
  int tid = threadIdx.x;
  const float* p1 = part + (size_t)AT*DM;
  const float* xs = x + (size_t)tok*DM;
  float xr[3];
  if (row == 0) {
    #pragma unroll
    for (int i = 0; i < 3; i++){ int c = tid + i*256;
      float acc = 0.0f;
      #pragma unroll
      for (int f = 0; f < SPACEF; f++){
        size_t r = ((size_t)(bi*SPACEF + f)*197)*DM + c;
        acc += part[r] + p1[r];
      }
      xr[i] = xs[c] + acc * 0.125f + bias[c];
    }
  } else {
    int t = (row - 1) >> 3, f = (row - 1) & 7;
    size_t r = ((size_t)((bi*SPACEF + f)*197) + 1 + t)*DM;
    #pragma unroll
    for (int i = 0; i < 3; i++){ int c = tid + i*256;
      xr[i] = xs[c] + part[r + c] + p1[r + c] + bias[c];
    }
  }
  float* xo = xnew + (size_t)tok*DM;
  #pragma unroll
  for (int i = 0; i < 3; i++) xo[tid + i*256] = xr[i];
  float mean = block_sum256(xr[0]+xr[1]+xr[2], sm) * (1.0f/768.0f);
  float v0 = xr[0]-mean, v1 = xr[1]-mean, v2 = xr[2]-mean;
  float var = block_sum256(v0*v0 + v1*v1 + v2*v2, sm) * (1.0f/768.0f);
  float rstd = rsqrtf(var + 1e-5f);
  bf16* o = out + (size_t)tok*DM;
  #pragma unroll
  for (int i = 0; i < 3; i++){ int c = tid + i*256;
    o[c] = __float2bfloat16((xr[i]-mean)*rstd*w[c] + b[c]); }
}

// ======= 4-wave 64x64 BK=64 GEMM, swizzled LDS, counted-vmcnt 2-phase, split-K =======
// skw==1: C = act(A @ Wsel^T + bias_sel)  (Wsel = m0<mhalf ? W0 : W1)
// skw>1 : fp32 partial at Cout[(z*M + row)*ldc + col]; K slice = KP, offset z*KP
template<int BM, int BN>
__global__ __launch_bounds__(256) void mgemm(
    const bf16* __restrict__ A, int lda,
    const bf16* __restrict__ W0, const bf16* __restrict__ W1, int ldw,
    const float* __restrict__ bias0, const float* __restrict__ bias1,
    void* __restrict__ Cout, int M, int mhalf, int N, int ldc, int KP,
    int act, int outbf16, int skw)
{
  constexpr int WM = BM/2, WN = BN/2, MI = WM/16, NJ = WN/16;
  static_assert(BM/32 + BN/32 == 4, "vmcnt literal assumes 4 loads/stage");
  __shared__ bf16 As[2][BM*64];
  __shared__ bf16 Bs[2][BN*64];
  int tid = threadIdx.x;
  int wave = tid >> 6, lane = tid & 63;

  // XCD-aware block placement. Assumes bid%8 round-robins XCDs.
  int gx = gridDim.x, gy = gridDim.y;
  int nwg = gx * gy;
  int bid = blockIdx.y * gx + blockIdx.x;
  int m0, n0;
  if ((gx & 3) == 0 && (gy & 1) == 0) {
    // 2D: each XCD owns a (gy/2) x (gx/4) rectangle
    int cw = gx >> 2, rh = gy >> 1;
    int xcd = bid & 7, lidx = bid >> 3;
    int rx = xcd & 3, ry = xcd >> 2;
    m0 = ((ry * rh) + lidx / cw) * BM;
    n0 = ((rx * cw) + lidx % cw) * BN;
  } else {
    // bijective linear chunk (cols fastest)
    int q = nwg >> 3, r = nwg & 7;
    int xcd = bid & 7, lidx = bid >> 3;
    int wg = (xcd < r ? xcd*(q+1) : r*(q+1) + (xcd-r)*q) + lidx;
    m0 = (wg / gx) * BM; n0 = (wg % gx) * BN;
  }

  int wr = wave >> 1, wc = wave & 1;

  int koff = blockIdx.z * KP;
  const bf16* Ak = A + koff;
  const bf16* Wt = ((m0 < mhalf) ? W0 : W1) + koff;
  const float* bias = (m0 < mhalf) ? bias0 : bias1;

  f32x4 acc[MI][NJ];
  #pragma unroll
  for (int i = 0; i < MI; i++)
    #pragma unroll
    for (int j = 0; j < NJ; j++) acc[i][j] = (f32x4){0.f,0.f,0.f,0.f};

  // staging: 8 rows x 128B per gld; source col pre-swizzled so linear LDS dest
  // equals swizzled layout (lds col block = (l&7)^(row&7)); read XORs it back.
  int sr8 = lane >> 3;
  int scs = (((lane & 7) ^ sr8) * 8);
  int lr16 = lane & 15, ks = (lane >> 4) * 8;
  int swz = (lr16 & 7) << 3;

  auto stage = [&](int buf, int k0){
    #pragma unroll
    for (int g = 0; g < BM/32; g++){
      int rr = wave*(BM/4) + g*8;
      const bf16* ga = Ak + (size_t)imin(m0 + rr + sr8, M-1)*lda + k0 + scs;
      GLD_LDS16(ga, &As[buf][rr*64]);
    }
    #pragma unroll
    for (int g = 0; g < BN/32; g++){
      int rr = wave*(BN/4) + g*8;
      const bf16* gb = Wt + (size_t)(n0 + rr + sr8)*ldw + k0 + scs;
      GLD_LDS16(gb, &Bs[buf][rr*64]);
    }
  };

  auto compute = [&](int buf){
    s16x8 afr[2][MI], bfr[2][NJ];
    #pragma unroll
    for (int kk = 0; kk < 2; kk++){
      #pragma unroll
      for (int i = 0; i < MI; i++)
        afr[kk][i] = *(const s16x8*)&As[buf][(wr*WM + i*16 + lr16)*64 + ((kk*32 + ks) ^ swz)];
      #pragma unroll
      for (int j = 0; j < NJ; j++)
        bfr[kk][j] = *(const s16x8*)&Bs[buf][(wc*WN + j*16 + lr16)*64 + ((kk*32 + ks) ^ swz)];
    }
    #pragma unroll
    for (int kk = 0; kk < 2; kk++)
      #pragma unroll
      for (int i = 0; i < MI; i++)
        #pragma unroll
        for (int j = 0; j < NJ; j++)
          acc[i][j] = __builtin_amdgcn_mfma_f32_16x16x32_bf16(afr[kk][i], bfr[kk][j], acc[i][j], 0, 0, 0);
  };

  // counted-vmcnt pipeline: next stage's 4 loads stay in flight across barriers.
  int nk = KP >> 6;
  stage(0, 0);
  int cur = 0;
  for (int k = 0; k < nk; ++k){
    if (k + 1 < nk) {
      stage(cur ^ 1, (k+1)*64);                       // 4 newer loads in flight
      asm volatile("s_waitcnt vmcnt(4)" ::: "memory"); // wait stage(k) only
    } else {
      asm volatile("s_waitcnt vmcnt(0)" ::: "memory");
    }
    __builtin_amdgcn_s_barrier();    // all waves: stage(k) landed
    compute(cur);
    __builtin_amdgcn_s_barrier();    // all waves done reading buf cur
    cur ^= 1;
  }

  #pragma unroll
  for (int i = 0; i < MI; i++){
    int rowb = m0 + wr*WM + i*16 + (lane >> 4)*4;
    #pragma unroll
    for (int j = 0; j < NJ; j++){
      int col = n0 + wc*WN + j*16 + lr16;
      if (col >= N) continue;
      float bv = bias ? bias[col] : 0.0f;
      #pragma unroll
      for (int r2 = 0; r2 < 4; r2++){
        int row = rowb + r2;
        if (row >= M) continue;
        float v = acc[i][j][r2];
        if (skw > 1){
          ((float*)Cout)[((size_t)(blockIdx.z*M) + row)*ldc + col] = v;
          continue;
        }
        v += bv;
        if (act == 1) v = geluf(v);
        else if (act == 2) v = softplusf(v);
        if (outbf16) ((bf16*)Cout)[(size_t)row*ldc + col] = __float2bfloat16(v);
        else         ((float*)Cout)[(size_t)row*ldc + col] = v;
      }
    }
  }
}

// ---------------- split-K reduce + epilogue (final output) ----------------
__global__ __launch_bounds__(256) void redk(
    const float* __restrict__ part, const float* __restrict__ bias,
    const float* __restrict__ resid, float* __restrict__ out,
    int M, int sk)
{
  int i = blockIdx.x*256 + threadIdx.x;
  if (i*4 >= M*768) return;
  int row = i / 192;
  int c4 = (i - row*192) * 4;
  size_t base = (size_t)row*768 + c4;
  float4 v = *(const float4*)(part + base);
  for (int z = 1; z < sk; z++){
    float4 p = *(const float4*)(part + (size_t)z*M*768 + base);
    v.x += p.x; v.y += p.y; v.z += p.z; v.w += p.w;
  }
  float4 bvec = *(const float4*)(bias + c4);
  float4 r = *(const float4*)(resid + base);
  v.x += bvec.x + r.x; v.y += bvec.y + r.y; v.z += bvec.z + r.z; v.w += bvec.w + r.w;
  *(float4*)(out + base) = v;
}

// ---------------- causal conv (D_CONV=4) + silu, both dirs (bf16 xz) ----------------
__global__ __launch_bounds__(256) void conv_kernel(
    const bf16* __restrict__ xz,
    const float* __restrict__ wf, const float* __restrict__ bf,
    const float* __restrict__ wb, const float* __restrict__ bb,
    bf16* __restrict__ xcf, bf16* __restrict__ xcb)
{
  int g = blockIdx.x*256 + threadIdx.x;
  if (g >= NSEQ*DM) return;
  int s = g / DM, d = g % DM;
  float xr[8];
  #pragma unroll
  for (int j = 0; j < 8; j++) xr[j] = __bfloat162float(xz[(size_t)(s*8 + j)*1536 + d]);
  float wfv[4], wbv[4];
  #pragma unroll
  for (int k = 0; k < 4; k++){ wfv[k] = wf[d*4+k]; wbv[k] = wb[d*4+k]; }
  float bfv = bf[d], bbv = bb[d];
  #pragma unroll
  for (int l = 0; l < 8; l++) {
    float af = bfv, ab = bbv;
    #pragma unroll
    for (int k = 0; k < 4; k++) {
      if (l + k >= 3) {
        af += wfv[k] * xr[l + k - 3];
        ab += wbv[k] * xr[10 - l - k];
      }
    }
    xcf[(size_t)(s*8 + l)*DM + d] = __float2bfloat16(silu_fast(af));
    xcb[(size_t)(s*8 + l)*DM + d] = __float2bfloat16(silu_fast(ab));
  }
}

// ---------------- SSM scan (both dirs fused, fast-exp, staged B/C) ----------------
__global__ __launch_bounds__(256) void ssm_kernel(
    const bf16* __restrict__ xz,
    const bf16* __restrict__ xcf, const bf16* __restrict__ xcb,
    const bf16* __restrict__ dblf, const bf16* __restrict__ dblb,
    const bf16* __restrict__ dlf, const bf16* __restrict__ dlb,
    const float* __restrict__ Alogf, const float* __restrict__ Df,
    const float* __restrict__ Alogb, const float* __restrict__ Db,
    bf16* __restrict__ y)
{
  int s = blockIdx.y;
  int d = blockIdx.x*256 + threadIdx.x;
  int tid = threadIdx.x;
  __shared__ float sBC[2][8][32];
  #pragma unroll
  for (int i = 0; i < 2; i++){
    int idx = tid + i*256;
    int dir = idx >> 8, r = idx & 255, l = r >> 5, j = r & 31;
    const bf16* p = dir ? dblb : dblf;
    sBC[dir][l][j] = __bfloat162float(p[(size_t)(s*8 + l)*80 + 48 + j]);
  }
  float Af[NSTATE], Ab[NSTATE];
  #pragma unroll
  for (int n = 0; n < NSTATE; n++) {
    Af[n] = -__expf(Alogf[d*NSTATE + n]);
    Ab[n] = -__expf(Alogb[d*NSTATE + n]);
  }
  float Dfv = Df[d], Dbv = Db[d];
  __syncthreads();

  float hf[NSTATE] = {}, hb[NSTATE] = {};
  float yf[8], yb[8];
  #pragma unroll
  for (int l = 0; l < 8; l++) {
    int t = s*8 + l;
    float delf = __bfloat162float(dlf[(size_t)t*DM + d]);
    float uf   = __bfloat162float(xcf[(size_t)t*DM + d]);
    float duf  = delf * uf;
    float accf = 0.0f;
    #pragma unroll
    for (int n = 0; n < NSTATE; n++) {
      hf[n] = __expf(delf*Af[n])*hf[n] + duf*sBC[0][l][n];
      accf += hf[n]*sBC[0][l][16+n];
    }
    yf[l] = accf + uf*Dfv;
    float delb = __bfloat162float(dlb[(size_t)t*DM + d]);
    float ub   = __bfloat162float(xcb[(size_t)t*DM + d]);
    float dub  = delb * ub;
    float accb = 0.0f;
    #pragma unroll
    for (int n = 0; n < NSTATE; n++) {
      hb[n] = __expf(delb*Ab[n])*hb[n] + dub*sBC[1][l][n];
      accb += hb[n]*sBC[1][l][16+n];
    }
    yb[7-l] = accb + ub*Dbv;
  }
  #pragma unroll
  for (int l = 0; l < 8; l++) {
    int t = s*8 + l;
    float zv = __bfloat162float(xz[(size_t)t*1536 + DM + d]);
    y[(size_t)t*DM + d] = __float2bfloat16((yf[l] + yb[l]) * silu_fast(zv));
  }
}

// ---------------- 16x16 attention over (b,f) slots, batched (pos, head) ----------------
__global__ __launch_bounds__(256) void attn_kernel(
    const bf16* __restrict__ qkv, bf16* __restrict__ ao)
{
  int n = blockIdx.x / 12, h = blockIdx.x % 12;
  __shared__ float qs[16][65], ks[16][65], vs[16][65], ps[16][17];
  int tid = threadIdx.x;
  for (int e = tid; e < 1024; e += 256) {
    int l = e >> 6, c = e & 63;
    size_t row = ((size_t)l*197 + n)*2304 + h*64 + c;
    qs[l][c] = __bfloat162float(qkv[row]);
    ks[l][c] = __bfloat162float(qkv[row + 768]);
    vs[l][c] = __bfloat162float(qkv[row + 1536]);
  }
  __syncthreads();
  int l = tid >> 4, m = tid & 15;
  float sc = 0.0f;
  #pragma unroll
  for (int c = 0; c < 64; c++) sc += qs[l][c]*ks[m][c];
  sc *= 0.125f;
  float mx = sc;
  #pragma unroll
  for (int o = 8; o > 0; o >>= 1) mx = fmaxf(mx, __shfl_xor(mx, o, 16));
  float p = __expf(sc - mx);
  float smv = p;
  #pragma unroll
  for (int o = 8; o > 0; o >>= 1) smv += __shfl_xor(smv, o, 16);
  ps[l][m] = __fdividef(p, smv);
  __syncthreads();
  for (int e = tid; e < 1024; e += 256) {
    int ll = e >> 6, c = e & 63;
    float acc = 0.0f;
    #pragma unroll
    for (int mm = 0; mm < 16; mm++) acc += ps[ll][mm]*vs[mm][c];
    ao[((size_t)ll*197 + n)*768 + h*64 + c] = __float2bfloat16(acc);
  }
}

extern "C" void kernel_launch(void* const* d_in, const int* in_sizes, int n_in,
                              void* d_out, int out_size, void* d_ws, size_t ws_size,
                              hipStream_t stream) {
  const float* x        = (const float*)d_in[0];
  const float* norm1_w  = (const float*)d_in[1];
  const float* norm1_b  = (const float*)d_in[2];
  const float* norm2_w  = (const float*)d_in[3];
  const float* norm2_b  = (const float*)d_in[4];
  const float* norm3_w  = (const float*)d_in[5];
  const float* norm3_b  = (const float*)d_in[6];
  const float* attn_in_w  = (const float*)d_in[7];
  const float* attn_in_b  = (const float*)d_in[8];
  const float* attn_out_w = (const float*)d_in[9];
  const float* attn_out_b = (const float*)d_in[10];
  const float* m_in_w   = (const float*)d_in[11];
  const float* m_conv_w = (const float*)d_in[12];
  const float* m_conv_b = (const float*)d_in[13];
  const float* m_xproj_w= (const float*)d_in[14];
  const float* m_dt_w   = (const float*)d_in[15];
  const float* m_dt_b   = (const float*)d_in[16];
  const float* m_Alog   = (const float*)d_in[17];
  const float* m_D      = (const float*)d_in[18];
  const float* m_conv_wb= (const float*)d_in[19];
  const float* m_conv_bb= (const float*)d_in[20];
  const float* m_xproj_wb=(const float*)d_in[21];
  const float* m_dt_wb  = (const float*)d_in[22];
  const float* m_dt_bb  = (const float*)d_in[23];
  const float* m_Alog_b = (const float*)d_in[24];
  const float* m_D_b    = (const float*)d_in[25];
  const float* m_out_w  = (const float*)d_in[26];
  const float* fc1_w    = (const float*)d_in[27];
  const float* fc1_b    = (const float*)d_in[28];
  const float* fc2_w    = (const float*)d_in[29];
  const float* fc2_b    = (const float*)d_in[30];

  char* wsb = (char*)d_ws;
  bf16*  wpool  = (bf16*)(wsb + 0);                 // [0, 18284544)
  bf16*  ln3    = (bf16*)(wsb + 18284544);          // 3136x768 bf16 (reused: y, ao)
  bf16*  xz     = (bf16*)(wsb + 23101440);          // 3136x1536 bf16 (9.63MB)
  bf16*  xcf    = (bf16*)(wsb + 42369024);
  bf16*  xcb    = (bf16*)(wsb + 47185920);
  bf16*  dblf   = (bf16*)(wsb + 52002816);
  bf16*  dblb   = (bf16*)(wsb + 52504576);
  bf16*  dlf    = (bf16*)(wsb + 53006336);
  bf16*  dlb    = (bf16*)(wsb + 57823232);          // ends 62640128
  bf16*  y      = ln3;
  float* part1  = (float*)(wsb + 23101440);         // outproj partials (xz dead after ssm)
  // phase 2
  bf16*  xsln   = (bf16*)(wsb + 62640128);
  bf16*  qkv    = (bf16*)(wsb + 42369024);
  bf16*  ao     = (bf16*)(wsb + 18284544);
  float* part2  = (float*)(wsb + 42369024);         // attn-out partials (qkv dead)
  float* xnew   = (float*)(wsb + 62640128);
  // phase 3
  bf16*  ln2o   = (bf16*)(wsb + 23101440);
  bf16*  h1     = (bf16*)(wsb + 42369024);
  float* part3  = (float*)(wsb + 18284544);

  bf16* w_in  = wpool + 0;
  bf16* w_xpf = wpool + 1179648;
  bf16* w_xpb = wpool + 1277952;
  bf16* w_dtf = wpool + 1376256;
  bf16* w_dtb = wpool + 1425408;
  bf16* w_out = wpool + 1474560;
  bf16* w_qkv = wpool + 2064384;
  bf16* w_ao  = wpool + 3833856;
  bf16* w_fc1 = wpool + 4423680;
  bf16* w_fc2 = wpool + 6782976;

  const int BIGM = 1 << 30;

  // weight convert + LN3 in one launch
  prep_kernel<<<dim3(3136, 11), 256, 0, stream>>>(
      m_in_w, m_xproj_w, m_xproj_wb, m_dt_w, m_dt_wb, m_out_w,
      attn_in_w, attn_out_w, fc1_w, fc2_w, wpool,
      x, norm3_w, norm3_b, ln3);

  // ===== phase 1: mamba over time tokens =====
  mgemm<64,64><<<dim3(24, 49), 256, 0, stream>>>(ln3, DM, w_in, w_in, DM,
      nullptr, nullptr, xz, MT, BIGM, 1536, 1536, DM, 0, 1, 1);
  conv_kernel<<<(NSEQ*DM + 255)/256, 256, 0, stream>>>(
      xz, m_conv_w, m_conv_b, m_conv_wb, m_conv_bb, xcf, xcb);
  mgemm<64,64><<<dim3(2, 98), 256, 0, stream>>>(xcf, DM, w_xpf, w_xpb, DM,
      nullptr, nullptr, dblf, 2*MT, MT, 80, 80, DM, 0, 1, 1);
  mgemm<64,64><<<dim3(12, 98), 256, 0, stream>>>(dblf, 80, w_dtf, w_dtb, 64,
      m_dt_b, m_dt_bb, dlf, 2*MT, MT, DM, DM, 64, 2, 1, 1);
  ssm_kernel<<<dim3(3, NSEQ), 256, 0, stream>>>(
      xz, xcf, xcb, dblf, dblb, dlf, dlb, m_Alog, m_D, m_Alog_b, m_D_b, y);
  mgemm<64,64><<<dim3(12, 49, 2), 256, 0, stream>>>(y, DM, w_out, w_out, DM,
      nullptr, nullptr, part1, MT, BIGM, DM, DM, 384, 0, 0, 2);

  // ===== phase 2: attention over space =====
  redk_ln<<<AT, 256, 0, stream>>>(part1, x, norm1_w, norm1_b, xsln);
  mgemm<64,64><<<dim3(36, 50), 256, 0, stream>>>(xsln, DM, w_qkv, w_qkv, DM,
      attn_in_b, attn_in_b, qkv, AT, BIGM, 2304, 2304, DM, 0, 1, 1);
  attn_kernel<<<197*12, 256, 0, stream>>>(qkv, ao);
  mgemm<64,64><<<dim3(12, 50, 2), 256, 0, stream>>>(ao, DM, w_ao, w_ao, DM,
      nullptr, nullptr, part2, AT, BIGM, DM, DM, 384, 0, 0, 2);

  // ===== phase 3: MLP =====
  scatter_ln<<<XTOK, 256, 0, stream>>>(part2, attn_out_b, x, xnew,
      norm2_w, norm2_b, ln2o);
  mgemm<64,64><<<dim3(48, 50), 256, 0, stream>>>(ln2o, DM, w_fc1, w_fc1, DM,
      fc1_b, fc1_b, h1, XTOK, BIGM, 3072, 3072, DM, 1, 1, 1);
  mgemm<64,64><<<dim3(12, 50, 2), 256, 0, stream>>>(h1, 3072, w_fc2, w_fc2, 3072,
      nullptr, nullptr, part3, XTOK, BIGM, DM, DM, 1536, 0, 0, 2);
  redk<<<2354, 256, 0, stream>>>(part3, fc2_b, xnew, (float*)d_out, XTOK, 2);
}